// Round 2
// baseline (171.275 us; speedup 1.0000x reference)
//
#include <hip/hip_runtime.h>

// Problem constants (from reference):
//   X:          [8][512][4096] f32
//   gates:      [8][8]          f32
//   core_first: [8][1][8][8]    f32   (E, r=1, m0, p)
//   cores_mid:  [6][8][8][8][8] f32   (i, E, r, m, p)
//   core_last:  [8][8][8][1]    f32   (E, r, n3, 1)
//   out:        [8][512][4096]  f32
//
// Math: per batch b, out[b] = (X[b] · Kin[b]) · Kout[b]  (rank-8 factorized map)
//   KinT [8][8][4096]  (b, p, m)  -- transposed for contiguous b128 reads
//   Kout [8][8][4096]  (b, p, n)

// ---------------------------------------------------------------------------
// k_compose: gate-merge the TT cores and materialize KinT / Kout.
// ---------------------------------------------------------------------------
__global__ __launch_bounds__(256) void k_compose(
    const float* __restrict__ gates,
    const float* __restrict__ core_first,
    const float* __restrict__ cores_mid,
    const float* __restrict__ core_last,
    float* __restrict__ KinT,  // [8][8][4096]
    float* __restrict__ Kout)  // [8][8][4096]
{
  const int part = blockIdx.x;   // 0..7 : m3 slice for Kin, n0 slice for Kout
  const int b    = blockIdx.y;
  const int t    = threadIdx.x;

  __shared__ float g[8];
  __shared__ float mg[3200];                     // merged cores
  __shared__ __align__(16) float A2[512];        // [(m1,m0)][p2]        stride 8 (broadcast reads)
  __shared__ __align__(16) float A3[512 * 9];    // [(m2,m1,m0)][p3]     stride 9 (anti-conflict)
  __shared__ __align__(16) float C2[512];        // [p6][(n2,n3)]
  __shared__ __align__(16) float C3[4096];       // [p5][(n1,n2,n3)]

  if (t < 8) g[t] = gates[b*8 + t];
  __syncthreads();

  for (int idx = t; idx < 3200; idx += 256) {
    float acc = 0.f;
    if (idx < 64) {
      #pragma unroll
      for (int e = 0; e < 8; ++e) acc += g[e] * core_first[e*64 + idx];
    } else if (idx < 3136) {
      const int i = (idx - 64) >> 9;
      const int w = (idx - 64) & 511;
      #pragma unroll
      for (int e = 0; e < 8; ++e) acc += g[e] * cores_mid[(i*8 + e)*512 + w];
    } else {
      const int w = idx - 3136;
      #pragma unroll
      for (int e = 0; e < 8; ++e) acc += g[e] * core_last[e*64 + w];
    }
    mg[idx] = acc;
  }
  __syncthreads();

  const float* mg0 = mg;
  const float* mg1 = mg + 64;
  const float* mg2 = mg + 64 + 512;
  const float* mg3 = mg + 64 + 1024;
  const float* mg4 = mg + 64 + 1536;
  const float* mg5 = mg + 64 + 2048;
  const float* mg6 = mg + 64 + 2560;
  const float* mg7 = mg + 3136;

  for (int idx = t; idx < 1024; idx += 256) {
    if (idx < 512) {
      const int mm = idx >> 3, p2 = idx & 7;
      const int m1 = mm >> 3, m0 = mm & 7;
      float acc = 0.f;
      #pragma unroll
      for (int p1 = 0; p1 < 8; ++p1)
        acc += mg0[m0*8 + p1] * mg1[p1*64 + m1*8 + p2];
      A2[idx] = acc;
    } else {
      const int id = idx - 512;
      const int p6 = id >> 6, n2 = (id >> 3) & 7, n3 = id & 7;
      float acc = 0.f;
      #pragma unroll
      for (int p7 = 0; p7 < 8; ++p7)
        acc += mg6[p6*64 + n2*8 + p7] * mg7[p7*8 + n3];
      C2[id] = acc;
    }
  }
  __syncthreads();

  for (int idx = t; idx < 8192; idx += 256) {
    if (idx < 4096) {
      const int rest = idx >> 3, p3 = idx & 7;
      const int m2 = rest >> 6, mm = rest & 63;
      float acc = 0.f;
      #pragma unroll
      for (int p2 = 0; p2 < 8; ++p2)
        acc += A2[mm*8 + p2] * mg2[p2*64 + m2*8 + p3];
      A3[rest*9 + p3] = acc;                        // padded stride 9
    } else {
      const int id = idx - 4096;
      const int p5 = id >> 9, n1 = (id >> 6) & 7, nn = id & 63;
      float acc = 0.f;
      #pragma unroll
      for (int p6 = 0; p6 < 8; ++p6)
        acc += mg5[p5*64 + n1*8 + p6] * C2[p6*64 + nn];
      C3[id] = acc;
    }
  }
  __syncthreads();

  {
    // KinT[b][p4][part*512 + r], r = rr*256 + t  -> lane-coalesced stores
    float* kb = KinT + b*32768;
    #pragma unroll
    for (int rr = 0; rr < 2; ++rr) {
      const int r = rr*256 + t;
      #pragma unroll
      for (int p4 = 0; p4 < 8; ++p4) {
        float acc = 0.f;
        #pragma unroll
        for (int p3 = 0; p3 < 8; ++p3)
          acc += A3[r*9 + p3] * mg3[p3*64 + part*8 + p4];
        kb[p4*4096 + part*512 + r] = acc;
      }
    }
    float* ob = Kout + b*32768 + part*512;
    #pragma unroll
    for (int jj = 0; jj < 2; ++jj) {
      const int j = jj*256 + t;
      #pragma unroll
      for (int p4 = 0; p4 < 8; ++p4) {
        float acc = 0.f;
        #pragma unroll
        for (int p5 = 0; p5 < 8; ++p5)
          acc += mg4[p4*64 + part*8 + p5] * C3[p5*512 + j];
        ob[p4*4096 + j] = acc;
      }
    }
  }
}

// ---------------------------------------------------------------------------
// k_fused: V = X·Kin (rank-8) then Out = V·Kout, one block per 8 s-rows.
//   256 threads = 4 waves; wave sp owns s-rows {s0+2sp, s0+2sp+1}; lane = m-part.
//   X is streamed straight from global (lanes cover consecutive float4s ->
//   1 KB/instr coalescing); only KinT is LDS-staged, 32 KB chunks,
//   reg-staged with issue-early / write-late split to hide HBM latency.
//   ds cost: 8 ds_read_b128 per 64 FMAs -> LDS pipe well under the HBM floor.
// ---------------------------------------------------------------------------
__global__ __launch_bounds__(256, 2) void k_fused(
    const float* __restrict__ X,
    const float* __restrict__ KinT,
    const float* __restrict__ Kout,
    float* __restrict__ Out)
{
  const int stile = blockIdx.x;       // 0..63, 8 s-rows each
  const int b     = blockIdx.y;       // 0..7
  const int t     = threadIdx.x;
  const int lane  = t & 63;
  const int sp    = t >> 6;           // wave id 0..3

  __shared__ __align__(16) float lkT[8 * 1024];   // KinT chunk [p][1024 m] (32 KB, linear)
  __shared__ __align__(16) float vs[8 * 8];       // V tile [s][p]

  const int s0 = stile * 8;

  // Stage mapping: thread t stages granule t of row p=i (idx = t + i*256 -> p=i, c=t).
  const float* ksrc = KinT + (size_t)b*32768 + t*4;
  float*       kdst = lkT + t*4;
  float4 R[8];

  float4 acc[2][8];
  #pragma unroll
  for (int s2 = 0; s2 < 2; ++s2)
    #pragma unroll
    for (int p = 0; p < 8; ++p) acc[s2][p] = make_float4(0.f, 0.f, 0.f, 0.f);

  const float* xb = X + ((size_t)(b*512 + s0 + sp*2)) * 4096 + lane*4;

  // Prologue: stage chunk 0.
  #pragma unroll
  for (int i = 0; i < 8; ++i) R[i] = *(const float4*)(ksrc + i*4096);
  #pragma unroll
  for (int i = 0; i < 8; ++i) *(float4*)(kdst + i*1024) = R[i];
  __syncthreads();

  #pragma unroll
  for (int mc = 0; mc < 4; ++mc) {
    if (mc < 3) {                       // issue next chunk's loads early (T14)
      #pragma unroll
      for (int i = 0; i < 8; ++i)
        R[i] = *(const float4*)(ksrc + i*4096 + (mc + 1)*1024);
    }
    #pragma unroll
    for (int j = 0; j < 4; ++j) {
      const float4 x0 = *(const float4*)(xb + (mc*256 + j*64)*4);
      const float4 x1 = *(const float4*)(xb + 4096 + (mc*256 + j*64)*4);
      #pragma unroll
      for (int p = 0; p < 8; ++p) {
        const float4 k = *(const float4*)(lkT + p*1024 + (j*64 + lane)*4);
        acc[0][p].x += x0.x*k.x; acc[0][p].y += x0.y*k.y;
        acc[0][p].z += x0.z*k.z; acc[0][p].w += x0.w*k.w;
        acc[1][p].x += x1.x*k.x; acc[1][p].y += x1.y*k.y;
        acc[1][p].z += x1.z*k.z; acc[1][p].w += x1.w*k.w;
      }
    }
    __syncthreads();                    // all waves done reading lkT
    if (mc < 3) {
      #pragma unroll
      for (int i = 0; i < 8; ++i) *(float4*)(kdst + i*1024) = R[i];
      __syncthreads();
    }
  }

  // Reduce over the 64 m-partitions (full-wave butterfly), write V tile.
  {
    float v[2][8];
    #pragma unroll
    for (int s2 = 0; s2 < 2; ++s2) {
      #pragma unroll
      for (int p = 0; p < 8; ++p) {
        float s = acc[s2][p].x + acc[s2][p].y + acc[s2][p].z + acc[s2][p].w;
        s += __shfl_xor(s, 1);
        s += __shfl_xor(s, 2);
        s += __shfl_xor(s, 4);
        s += __shfl_xor(s, 8);
        s += __shfl_xor(s, 16);
        s += __shfl_xor(s, 32);
        v[s2][p] = s;
      }
    }
    if (lane == 0) {
      #pragma unroll
      for (int s2 = 0; s2 < 2; ++s2)
        #pragma unroll
        for (int p = 0; p < 8; ++p)
          vs[(sp*2 + s2)*8 + p] = v[s2][p];
    }
  }
  __syncthreads();

  // Out phase: Out[b][s0+s][n] = sum_p V[s][p] * Kout[b][p][n].  Write-bound.
  float4 vA[8], vB[8];
  #pragma unroll
  for (int s = 0; s < 8; ++s) {
    vA[s] = *(const float4*)(vs + s*8);       // p 0..3 (broadcast reads)
    vB[s] = *(const float4*)(vs + s*8 + 4);   // p 4..7
  }

  const float* kob = Kout + (size_t)b*32768 + t*4;
  float*       ob  = Out + ((size_t)(b*512 + s0))*4096 + t*4;

  #pragma unroll
  for (int nc = 0; nc < 4; ++nc) {
    float4 kr[8];
    #pragma unroll
    for (int p = 0; p < 8; ++p)
      kr[p] = *(const float4*)(kob + p*4096 + nc*1024);   // L2-hot, coalesced
    #pragma unroll
    for (int s = 0; s < 8; ++s) {
      float4 o;
      o.x = vA[s].x*kr[0].x + vA[s].y*kr[1].x + vA[s].z*kr[2].x + vA[s].w*kr[3].x
          + vB[s].x*kr[4].x + vB[s].y*kr[5].x + vB[s].z*kr[6].x + vB[s].w*kr[7].x;
      o.y = vA[s].x*kr[0].y + vA[s].y*kr[1].y + vA[s].z*kr[2].y + vA[s].w*kr[3].y
          + vB[s].x*kr[4].y + vB[s].y*kr[5].y + vB[s].z*kr[6].y + vB[s].w*kr[7].y;
      o.z = vA[s].x*kr[0].z + vA[s].y*kr[1].z + vA[s].z*kr[2].z + vA[s].w*kr[3].z
          + vB[s].x*kr[4].z + vB[s].y*kr[5].z + vB[s].z*kr[6].z + vB[s].w*kr[7].z;
      o.w = vA[s].x*kr[0].w + vA[s].y*kr[1].w + vA[s].z*kr[2].w + vA[s].w*kr[3].w
          + vB[s].x*kr[4].w + vB[s].y*kr[5].w + vB[s].z*kr[6].w + vB[s].w*kr[7].w;
      *(float4*)(ob + (size_t)s*4096 + nc*1024) = o;
    }
  }
}

extern "C" void kernel_launch(void* const* d_in, const int* in_sizes, int n_in,
                              void* d_out, int out_size, void* d_ws, size_t ws_size,
                              hipStream_t stream) {
  const float* X     = (const float*)d_in[0];
  const float* gates = (const float*)d_in[1];
  const float* cf    = (const float*)d_in[2];
  const float* cm    = (const float*)d_in[3];
  const float* cl    = (const float*)d_in[4];
  float* out = (float*)d_out;

  float* ws   = (float*)d_ws;
  float* KinT = ws;                 // 262144 floats (1 MB)
  float* Kout = ws + 262144;        // 262144 floats (1 MB)

  k_compose<<<dim3(8, 8),  256, 0, stream>>>(gates, cf, cm, cl, KinT, Kout);
  k_fused <<<dim3(64, 8), 256, 0, stream>>>(X, KinT, Kout, out);
}